// Round 1
// baseline (3449.216 us; speedup 1.0000x reference)
//
#include <hip/hip_runtime.h>
#include <cstddef>

// Problem constants
#define NB 512   // batch
#define NT 64    // encoder timesteps
#define NIN 512  // input feature dim
#define NH 512   // hidden
#define NC 96    // classes
#define NS 26    // decode steps

__device__ __forceinline__ float tanh_fast(float x) {
    // 1 - 2/(e^{2x}+1); robust at +-inf
    return 1.f - 2.f / (__expf(2.f * x) + 1.f);
}
__device__ __forceinline__ float sigf(float x) {
    return 1.f / (1.f + __expf(-x));
}

// ---------------------------------------------------------------------------
// Generic fp32 NT GEMM: C[M,N] = A[M,K](lda) * B[N,K](ldb)^T  (+ bias[n])
// Block tile 64x64, BK=16, 256 threads, 4x4 per thread.
// Grid: (N/64, M/64). K multiple of 16, M,N multiples of 64.
// MODE: 0 = none, 1 = +bias[n]
// ---------------------------------------------------------------------------
template <int MODE>
__global__ __launch_bounds__(256) void gemm64(
    const float* __restrict__ A, int lda,
    const float* __restrict__ Bm, int ldb,
    float* __restrict__ C, int ldc,
    const float* __restrict__ bias, int K)
{
    __shared__ float As[16][64];
    __shared__ float Bs[16][64];
    const int bm = blockIdx.y * 64;
    const int bn = blockIdx.x * 64;
    const int tid = threadIdx.x;
    const int tx = tid & 15, ty = tid >> 4;
    const int arow = tid >> 2;          // 0..63
    const int ac4 = (tid & 3) * 4;      // k offset within 16-tile

    const float* Aptr = A + (size_t)(bm + arow) * lda + ac4;
    const float* Bptr = Bm + (size_t)(bn + arow) * ldb + ac4;

    float acc[4][4] = {};
    for (int k0 = 0; k0 < K; k0 += 16) {
        const float4 av = *(const float4*)(Aptr + k0);
        const float4 bv = *(const float4*)(Bptr + k0);
        __syncthreads();
        As[ac4 + 0][arow] = av.x; As[ac4 + 1][arow] = av.y;
        As[ac4 + 2][arow] = av.z; As[ac4 + 3][arow] = av.w;
        Bs[ac4 + 0][arow] = bv.x; Bs[ac4 + 1][arow] = bv.y;
        Bs[ac4 + 2][arow] = bv.z; Bs[ac4 + 3][arow] = bv.w;
        __syncthreads();
#pragma unroll
        for (int kk = 0; kk < 16; ++kk) {
            const float4 a = *(const float4*)&As[kk][ty * 4];
            const float4 b = *(const float4*)&Bs[kk][tx * 4];
            acc[0][0] = fmaf(a.x, b.x, acc[0][0]);
            acc[0][1] = fmaf(a.x, b.y, acc[0][1]);
            acc[0][2] = fmaf(a.x, b.z, acc[0][2]);
            acc[0][3] = fmaf(a.x, b.w, acc[0][3]);
            acc[1][0] = fmaf(a.y, b.x, acc[1][0]);
            acc[1][1] = fmaf(a.y, b.y, acc[1][1]);
            acc[1][2] = fmaf(a.y, b.z, acc[1][2]);
            acc[1][3] = fmaf(a.y, b.w, acc[1][3]);
            acc[2][0] = fmaf(a.z, b.x, acc[2][0]);
            acc[2][1] = fmaf(a.z, b.y, acc[2][1]);
            acc[2][2] = fmaf(a.z, b.z, acc[2][2]);
            acc[2][3] = fmaf(a.z, b.w, acc[2][3]);
            acc[3][0] = fmaf(a.w, b.x, acc[3][0]);
            acc[3][1] = fmaf(a.w, b.y, acc[3][1]);
            acc[3][2] = fmaf(a.w, b.z, acc[3][2]);
            acc[3][3] = fmaf(a.w, b.w, acc[3][3]);
        }
    }
#pragma unroll
    for (int i = 0; i < 4; ++i) {
#pragma unroll
        for (int j = 0; j < 4; ++j) {
            const int m = bm + ty * 4 + i;
            const int n = bn + tx * 4 + j;
            float v = acc[i][j];
            if (MODE == 1) v += bias[n];
            C[(size_t)m * ldc + n] = v;
        }
    }
}

// ---------------------------------------------------------------------------
// Gates GEMM: gates[512,2048] = ctx[512,512] @ W_ih[:, :512]^T
//                             + hprev[512,512](ldh) @ W_hh^T
//                             + b_ih[n] + b_hh[n] + W_ih[n, 512 + text[m,s]]
// K = 1024 virtual concat. Grid: (2048/64, 512/64).
// ---------------------------------------------------------------------------
__global__ __launch_bounds__(256) void gemm_gates(
    const float* __restrict__ ctx,
    const float* __restrict__ hprev, int ldh,
    const float* __restrict__ W_ih,   // [2048, 608]
    const float* __restrict__ W_hh,   // [2048, 512]
    const float* __restrict__ b_ih,
    const float* __restrict__ b_hh,
    const int* __restrict__ text,     // [512, 26]
    int sstep,
    float* __restrict__ gates)        // [512, 2048]
{
    __shared__ float As[16][64];
    __shared__ float Bs[16][64];
    const int bm = blockIdx.y * 64;
    const int bn = blockIdx.x * 64;
    const int tid = threadIdx.x;
    const int tx = tid & 15, ty = tid >> 4;
    const int arow = tid >> 2;
    const int ac4 = (tid & 3) * 4;

    float acc[4][4] = {};
    for (int k0 = 0; k0 < 1024; k0 += 16) {
        const float* Ap; const float* Bp; int la, lb, kk;
        if (k0 < 512) { Ap = ctx;   la = 512; Bp = W_ih; lb = 608; kk = k0; }
        else          { Ap = hprev; la = ldh; Bp = W_hh; lb = 512; kk = k0 - 512; }
        const float4 av = *(const float4*)(Ap + (size_t)(bm + arow) * la + kk + ac4);
        const float4 bv = *(const float4*)(Bp + (size_t)(bn + arow) * lb + kk + ac4);
        __syncthreads();
        As[ac4 + 0][arow] = av.x; As[ac4 + 1][arow] = av.y;
        As[ac4 + 2][arow] = av.z; As[ac4 + 3][arow] = av.w;
        Bs[ac4 + 0][arow] = bv.x; Bs[ac4 + 1][arow] = bv.y;
        Bs[ac4 + 2][arow] = bv.z; Bs[ac4 + 3][arow] = bv.w;
        __syncthreads();
#pragma unroll
        for (int kk2 = 0; kk2 < 16; ++kk2) {
            const float4 a = *(const float4*)&As[kk2][ty * 4];
            const float4 b = *(const float4*)&Bs[kk2][tx * 4];
            acc[0][0] = fmaf(a.x, b.x, acc[0][0]);
            acc[0][1] = fmaf(a.x, b.y, acc[0][1]);
            acc[0][2] = fmaf(a.x, b.z, acc[0][2]);
            acc[0][3] = fmaf(a.x, b.w, acc[0][3]);
            acc[1][0] = fmaf(a.y, b.x, acc[1][0]);
            acc[1][1] = fmaf(a.y, b.y, acc[1][1]);
            acc[1][2] = fmaf(a.y, b.z, acc[1][2]);
            acc[1][3] = fmaf(a.y, b.w, acc[1][3]);
            acc[2][0] = fmaf(a.z, b.x, acc[2][0]);
            acc[2][1] = fmaf(a.z, b.y, acc[2][1]);
            acc[2][2] = fmaf(a.z, b.z, acc[2][2]);
            acc[2][3] = fmaf(a.z, b.w, acc[2][3]);
            acc[3][0] = fmaf(a.w, b.x, acc[3][0]);
            acc[3][1] = fmaf(a.w, b.y, acc[3][1]);
            acc[3][2] = fmaf(a.w, b.z, acc[3][2]);
            acc[3][3] = fmaf(a.w, b.w, acc[3][3]);
        }
    }
#pragma unroll
    for (int i = 0; i < 4; ++i) {
        const int m = bm + ty * 4 + i;
        const int tok = text[m * NS + sstep];
#pragma unroll
        for (int j = 0; j < 4; ++j) {
            const int n = bn + tx * 4 + j;
            float v = acc[i][j] + b_ih[n] + b_hh[n] + W_ih[(size_t)n * 608 + 512 + tok];
            gates[(size_t)m * 2048 + n] = v;
        }
    }
}

// ---------------------------------------------------------------------------
// Attention: per block b -> e[t] = sum_h tanh(H_proj[b,t,h]+ph[b,h])*w[h],
// softmax over t, context[b,d] = sum_t alpha[t]*batch_H[b,t,d]
// ---------------------------------------------------------------------------
__global__ __launch_bounds__(256) void attn_kernel(
    const float* __restrict__ H_proj,   // [B*T, 512]
    const float* __restrict__ ph,       // [B, 512]
    const float* __restrict__ w_score,  // [512]
    const float* __restrict__ batch_H,  // [B*T, 512]
    float* __restrict__ context)        // [B, 512]
{
    __shared__ float s_ph[512];
    __shared__ float s_w[512];
    __shared__ float s_e[64];
    __shared__ float s_al[64];
    const int b = blockIdx.x;
    const int tid = threadIdx.x;
    s_ph[tid] = ph[b * 512 + tid];
    s_ph[tid + 256] = ph[b * 512 + 256 + tid];
    s_w[tid] = w_score[tid];
    s_w[tid + 256] = w_score[tid + 256];
    __syncthreads();

    const int w = tid >> 6, lane = tid & 63;
    for (int t = w; t < 64; t += 4) {
        const float* Hp = H_proj + ((size_t)b * 64 + t) * 512 + lane * 8;
        const float4 a0 = *(const float4*)Hp;
        const float4 a1 = *(const float4*)(Hp + 4);
        const int h0 = lane * 8;
        float acc;
        acc  = tanh_fast(a0.x + s_ph[h0 + 0]) * s_w[h0 + 0];
        acc += tanh_fast(a0.y + s_ph[h0 + 1]) * s_w[h0 + 1];
        acc += tanh_fast(a0.z + s_ph[h0 + 2]) * s_w[h0 + 2];
        acc += tanh_fast(a0.w + s_ph[h0 + 3]) * s_w[h0 + 3];
        acc += tanh_fast(a1.x + s_ph[h0 + 4]) * s_w[h0 + 4];
        acc += tanh_fast(a1.y + s_ph[h0 + 5]) * s_w[h0 + 5];
        acc += tanh_fast(a1.z + s_ph[h0 + 6]) * s_w[h0 + 6];
        acc += tanh_fast(a1.w + s_ph[h0 + 7]) * s_w[h0 + 7];
#pragma unroll
        for (int off = 32; off; off >>= 1) acc += __shfl_xor(acc, off);
        if (lane == 0) s_e[t] = acc;
    }
    __syncthreads();
    if (tid < 64) {
        float m = -1e30f;
        for (int t = 0; t < 64; ++t) m = fmaxf(m, s_e[t]);
        float sum = 0.f;
        for (int t = 0; t < 64; ++t) sum += __expf(s_e[t] - m);
        s_al[tid] = __expf(s_e[tid] - m) / sum;
    }
    __syncthreads();
    float acc0 = 0.f, acc1 = 0.f;
    const float* Bp = batch_H + (size_t)b * 64 * 512;
    for (int t = 0; t < 64; ++t) {
        const float al = s_al[t];
        acc0 = fmaf(al, Bp[t * 512 + tid], acc0);
        acc1 = fmaf(al, Bp[t * 512 + 256 + tid], acc1);
    }
    context[b * 512 + tid] = acc0;
    context[b * 512 + 256 + tid] = acc1;
}

// ---------------------------------------------------------------------------
// LSTM pointwise: gates[512,2048] (i,f,g,o) + c -> c_new, hs[:, s, :]
// ---------------------------------------------------------------------------
__global__ __launch_bounds__(256) void lstm_pw(
    const float* __restrict__ gates,
    float* __restrict__ c,
    float* __restrict__ hs,   // [B, NS, 512]
    int sstep)
{
    const int idx = blockIdx.x * 256 + threadIdx.x;   // 0 .. 512*512-1
    const int b = idx >> 9, hcol = idx & 511;
    const float* g = gates + (size_t)b * 2048;
    const float i_ = sigf(g[hcol]);
    const float f_ = sigf(g[512 + hcol]);
    const float g_ = tanh_fast(g[1024 + hcol]);
    const float o_ = sigf(g[1536 + hcol]);
    const float cn = fmaf(f_, c[idx], i_ * g_);
    c[idx] = cn;
    hs[((size_t)b * NS + sstep) * 512 + hcol] = o_ * tanh_fast(cn);
}

// ---------------------------------------------------------------------------
// Generator: out[row, c] = hs[row,:] . W_gen[c,:] + b_gen[c], row = b*26+s
// ---------------------------------------------------------------------------
__global__ __launch_bounds__(128) void gen_kernel(
    const float* __restrict__ hs,
    const float* __restrict__ W_gen,   // [96, 512]
    const float* __restrict__ b_gen,
    float* __restrict__ out)           // [B*NS, 96]
{
    __shared__ float sh[512];
    const int row = blockIdx.x;
    const int tid = threadIdx.x;
#pragma unroll
    for (int j = 0; j < 4; ++j) sh[tid + j * 128] = hs[(size_t)row * 512 + tid + j * 128];
    __syncthreads();
    if (tid < 96) {
        const float* wg = W_gen + (size_t)tid * 512;
        float acc = b_gen[tid];
        for (int k = 0; k < 512; k += 4) {
            const float4 wv = *(const float4*)(wg + k);
            acc = fmaf(sh[k + 0], wv.x, acc);
            acc = fmaf(sh[k + 1], wv.y, acc);
            acc = fmaf(sh[k + 2], wv.z, acc);
            acc = fmaf(sh[k + 3], wv.w, acc);
        }
        out[(size_t)row * 96 + tid] = acc;
    }
}

// ---------------------------------------------------------------------------
extern "C" void kernel_launch(void* const* d_in, const int* in_sizes, int n_in,
                              void* d_out, int out_size, void* d_ws, size_t ws_size,
                              hipStream_t stream) {
    const float* batch_H = (const float*)d_in[0];   // [512,64,512]
    const int*   text    = (const int*)d_in[1];     // [512,26]
    const float* W_i2h   = (const float*)d_in[2];   // [512,512]
    const float* W_h2h   = (const float*)d_in[3];   // [512,512]
    const float* b_h2h   = (const float*)d_in[4];   // [512]
    const float* w_score = (const float*)d_in[5];   // [1,512]
    const float* W_ih    = (const float*)d_in[6];   // [2048,608]
    const float* b_ih    = (const float*)d_in[7];   // [2048]
    const float* W_hh    = (const float*)d_in[8];   // [2048,512]
    const float* b_hh    = (const float*)d_in[9];   // [2048]
    const float* W_gen   = (const float*)d_in[10];  // [96,512]
    const float* b_gen   = (const float*)d_in[11];  // [96]
    float* out = (float*)d_out;                     // [512,26,96]

    float* ws = (float*)d_ws;
    float* H_proj = ws;                                   // 32768*512
    float* hs     = H_proj + (size_t)32768 * 512;         // 512*26*512
    float* h0z    = hs + (size_t)512 * NS * 512;          // 512*512
    float* c      = h0z + (size_t)512 * 512;              // 512*512
    float* ph     = c + (size_t)512 * 512;                // 512*512
    float* ctx    = ph + (size_t)512 * 512;               // 512*512
    float* gates  = ctx + (size_t)512 * 512;              // 512*2048

    hipMemsetAsync(h0z, 0, (size_t)512 * 512 * sizeof(float), stream);
    hipMemsetAsync(c, 0, (size_t)512 * 512 * sizeof(float), stream);

    // H_proj = batch_H @ W_i2h^T   [32768, 512]
    gemm64<0><<<dim3(NH / 64, 32768 / 64), 256, 0, stream>>>(
        batch_H, NIN, W_i2h, NIN, H_proj, NH, nullptr, NIN);

    for (int s = 0; s < NS; ++s) {
        const float* hprev;
        int ldh;
        if (s == 0) { hprev = h0z; ldh = 512; }
        else        { hprev = hs + (size_t)(s - 1) * 512; ldh = NS * 512; }

        // ph = hprev @ W_h2h^T + b_h2h
        gemm64<1><<<dim3(NH / 64, NB / 64), 256, 0, stream>>>(
            hprev, ldh, W_h2h, NH, ph, NH, b_h2h, NH);

        attn_kernel<<<NB, 256, 0, stream>>>(H_proj, ph, w_score, batch_H, ctx);

        gemm_gates<<<dim3(2048 / 64, NB / 64), 256, 0, stream>>>(
            ctx, hprev, ldh, W_ih, W_hh, b_ih, b_hh, text, s, gates);

        lstm_pw<<<(NB * NH) / 256, 256, 0, stream>>>(gates, c, hs, s);
    }

    gen_kernel<<<NB * NS, 128, 0, stream>>>(hs, W_gen, b_gen, out);
}

// Round 2
// 1132.922 us; speedup vs baseline: 3.0445x; 3.0445x over previous
//
#include <hip/hip_runtime.h>
#include <cstddef>

#define NS 26

typedef short bf16x8 __attribute__((ext_vector_type(8)));
typedef float f32x4 __attribute__((ext_vector_type(4)));

__device__ __forceinline__ float tanh_fast(float x) { return 1.f - 2.f / (__expf(2.f * x) + 1.f); }
__device__ __forceinline__ float sigf(float x) { return 1.f / (1.f + __expf(-x)); }
__device__ __forceinline__ unsigned short f2bf(float x) {
    unsigned int u = __float_as_uint(x);
    return (unsigned short)((u + 0x7FFFu + ((u >> 16) & 1u)) >> 16);
}

// ---------------- fp32 -> bf16 converts ----------------
__global__ __launch_bounds__(256) void conv_f32_bf16(const float* __restrict__ s,
                                                     unsigned short* __restrict__ d, int n4) {
    int i = blockIdx.x * 256 + threadIdx.x;
    if (i >= n4) return;
    float4 v = ((const float4*)s)[i];
    ushort4 o; o.x = f2bf(v.x); o.y = f2bf(v.y); o.z = f2bf(v.z); o.w = f2bf(v.w);
    ((ushort4*)d)[i] = o;
}
// W_ih[2048][608] -> first 512 cols as bf16 [2048][512]
__global__ __launch_bounds__(256) void conv_wih(const float* __restrict__ W,
                                                unsigned short* __restrict__ d) {
    int i = blockIdx.x * 256 + threadIdx.x;   // 2048*128 float4 groups
    int row = i >> 7, c4 = (i & 127) << 2;
    float4 v = *(const float4*)(W + (size_t)row * 608 + c4);
    ushort4 o; o.x = f2bf(v.x); o.y = f2bf(v.y); o.z = f2bf(v.z); o.w = f2bf(v.w);
    *(ushort4*)(d + (size_t)row * 512 + c4) = o;
}

// ---------------------------------------------------------------------------
// bf16 NT MFMA GEMM: C[M,N] = A[M,K](lda) * B[N,K](ldb)^T
// 64x64 tile, BK=64, 256 thr = 4 waves (2x2), each wave 32x32 (2x2 frags of 16x16).
// Double-buffered LDS [64][72] (padded: 2-way bank conflicts only), 2-phase pipeline.
// MODE 0: bf16 out, no bias. MODE 1: f32 out + bias. MODE 3: f32 out + bias, cols masked n<Nreal.
// ---------------------------------------------------------------------------
template <int MODE>
__global__ __launch_bounds__(256) void gemm_bf16(
    const unsigned short* __restrict__ A, int lda,
    const unsigned short* __restrict__ B, int ldb,
    void* __restrict__ Cout, int ldc,
    const float* __restrict__ bias, int K, int Nreal)
{
    __shared__ unsigned short As[2][64][72];
    __shared__ unsigned short Bs[2][64][72];
    const int tid = threadIdx.x;
    const int bm = blockIdx.y << 6, bn = blockIdx.x << 6;
    const int w = tid >> 6, lane = tid & 63;
    const int wr = w >> 1, wc = w & 1;
    const int srow = tid >> 2, schunk = (tid & 3) << 4;
    int brow = bn + srow;
    if (MODE == 3) brow = min(brow, Nreal - 1);
    const unsigned short* Ap = A + (size_t)(bm + srow) * lda + schunk;
    const unsigned short* Bp = B + (size_t)brow * ldb + schunk;
    const int fr = lane & 15, fq = lane >> 4;

    uint4 ra0, ra1, rb0, rb1;
    f32x4 acc[2][2];
#pragma unroll
    for (int i = 0; i < 2; i++)
#pragma unroll
        for (int j = 0; j < 2; j++) acc[i][j] = f32x4{0.f, 0.f, 0.f, 0.f};

    const int NTk = K >> 6;
#define LOADR(t) { ra0 = *(const uint4*)(Ap + ((t) << 6)); ra1 = *(const uint4*)(Ap + ((t) << 6) + 8); \
                   rb0 = *(const uint4*)(Bp + ((t) << 6)); rb1 = *(const uint4*)(Bp + ((t) << 6) + 8); }
#define WRITEB(cb) { *(uint4*)&As[cb][srow][schunk] = ra0; *(uint4*)&As[cb][srow][schunk + 8] = ra1; \
                     *(uint4*)&Bs[cb][srow][schunk] = rb0; *(uint4*)&Bs[cb][srow][schunk + 8] = rb1; }
    LOADR(0); WRITEB(0);
    LOADR(1);
    __syncthreads();
    for (int t = 0; t < NTk; t++) {
        const int cb = t & 1;
        if (t + 1 < NTk) WRITEB(cb ^ 1);
        if (t + 2 < NTk) LOADR(t + 2);
        bf16x8 af[2][2], bfr[2][2];
#pragma unroll
        for (int fi = 0; fi < 2; fi++)
#pragma unroll
            for (int ks = 0; ks < 2; ks++) {
                af[fi][ks]  = *(const bf16x8*)&As[cb][(wr << 5) + (fi << 4) + fr][(ks << 5) + (fq << 3)];
                bfr[fi][ks] = *(const bf16x8*)&Bs[cb][(wc << 5) + (fi << 4) + fr][(ks << 5) + (fq << 3)];
            }
#pragma unroll
        for (int fi = 0; fi < 2; fi++)
#pragma unroll
            for (int fj = 0; fj < 2; fj++)
#pragma unroll
                for (int ks = 0; ks < 2; ks++)
                    acc[fi][fj] = __builtin_amdgcn_mfma_f32_16x16x32_bf16(
                        af[fi][ks], bfr[fj][ks], acc[fi][fj], 0, 0, 0);
        __syncthreads();
    }
#undef LOADR
#undef WRITEB
    // epilogue: C/D layout col = lane&15, row = (lane>>4)*4 + r  [m89-verified]
#pragma unroll
    for (int fi = 0; fi < 2; fi++) {
        const int mbase = bm + (wr << 5) + (fi << 4) + (fq << 2);
#pragma unroll
        for (int fj = 0; fj < 2; fj++) {
            const int n = bn + (wc << 5) + (fj << 4) + fr;
            f32x4 v = acc[fi][fj];
            if (MODE == 0) {
                unsigned short* C = (unsigned short*)Cout;
#pragma unroll
                for (int r = 0; r < 4; r++) C[(size_t)(mbase + r) * ldc + n] = f2bf(v[r]);
            } else if (MODE == 1) {
                float* C = (float*)Cout;
                const float bb = bias[n];
#pragma unroll
                for (int r = 0; r < 4; r++) C[(size_t)(mbase + r) * ldc + n] = v[r] + bb;
            } else {
                if (n < Nreal) {
                    float* C = (float*)Cout;
                    const float bb = bias[n];
#pragma unroll
                    for (int r = 0; r < 4; r++) C[(size_t)(mbase + r) * ldc + n] = v[r] + bb;
                }
            }
        }
    }
}

// ---------------------------------------------------------------------------
// gates[512,2048] = ctx@W_ihc^T + hprev@W_hh^T + b_ih + b_hh + W_ih[:,512+tok]
// Same structure, K=1024 virtual concat (8 iters ctx half, 8 iters h half).
// ---------------------------------------------------------------------------
__global__ __launch_bounds__(256) void gemm_gates_mfma(
    const unsigned short* __restrict__ ctx,
    const unsigned short* __restrict__ hprev, int ldh,
    const unsigned short* __restrict__ Wihc,
    const unsigned short* __restrict__ Whh,
    const float* __restrict__ W_ih_f32,
    const float* __restrict__ b_ih,
    const float* __restrict__ b_hh,
    const int* __restrict__ text, int sstep,
    float* __restrict__ gates)
{
    __shared__ unsigned short As[2][64][72];
    __shared__ unsigned short Bs[2][64][72];
    const int tid = threadIdx.x;
    const int bm = blockIdx.y << 6, bn = blockIdx.x << 6;
    const int w = tid >> 6, lane = tid & 63;
    const int wr = w >> 1, wc = w & 1;
    const int srow = tid >> 2, schunk = (tid & 3) << 4;
    const unsigned short* Apc = ctx + (size_t)(bm + srow) * 512 + schunk;
    const unsigned short* Aph = hprev + (size_t)(bm + srow) * ldh + schunk;
    const unsigned short* Bpc = Wihc + (size_t)(bn + srow) * 512 + schunk;
    const unsigned short* Bph = Whh + (size_t)(bn + srow) * 512 + schunk;
    const int fr = lane & 15, fq = lane >> 4;

    uint4 ra0, ra1, rb0, rb1;
    f32x4 acc[2][2];
#pragma unroll
    for (int i = 0; i < 2; i++)
#pragma unroll
        for (int j = 0; j < 2; j++) acc[i][j] = f32x4{0.f, 0.f, 0.f, 0.f};

#define LOADG(t) { const int tt = (t); \
    const unsigned short* ap = (tt < 8) ? Apc + (tt << 6) : Aph + ((tt - 8) << 6); \
    const unsigned short* bp = (tt < 8) ? Bpc + (tt << 6) : Bph + ((tt - 8) << 6); \
    ra0 = *(const uint4*)ap; ra1 = *(const uint4*)(ap + 8); \
    rb0 = *(const uint4*)bp; rb1 = *(const uint4*)(bp + 8); }
#define WRITEB(cb) { *(uint4*)&As[cb][srow][schunk] = ra0; *(uint4*)&As[cb][srow][schunk + 8] = ra1; \
                     *(uint4*)&Bs[cb][srow][schunk] = rb0; *(uint4*)&Bs[cb][srow][schunk + 8] = rb1; }
    LOADG(0); WRITEB(0);
    LOADG(1);
    __syncthreads();
    for (int t = 0; t < 16; t++) {
        const int cb = t & 1;
        if (t + 1 < 16) WRITEB(cb ^ 1);
        if (t + 2 < 16) LOADG(t + 2);
        bf16x8 af[2][2], bfr[2][2];
#pragma unroll
        for (int fi = 0; fi < 2; fi++)
#pragma unroll
            for (int ks = 0; ks < 2; ks++) {
                af[fi][ks]  = *(const bf16x8*)&As[cb][(wr << 5) + (fi << 4) + fr][(ks << 5) + (fq << 3)];
                bfr[fi][ks] = *(const bf16x8*)&Bs[cb][(wc << 5) + (fi << 4) + fr][(ks << 5) + (fq << 3)];
            }
#pragma unroll
        for (int fi = 0; fi < 2; fi++)
#pragma unroll
            for (int fj = 0; fj < 2; fj++)
#pragma unroll
                for (int ks = 0; ks < 2; ks++)
                    acc[fi][fj] = __builtin_amdgcn_mfma_f32_16x16x32_bf16(
                        af[fi][ks], bfr[fj][ks], acc[fi][fj], 0, 0, 0);
        __syncthreads();
    }
#undef LOADG
#undef WRITEB
#pragma unroll
    for (int fi = 0; fi < 2; fi++) {
        const int mbase = bm + (wr << 5) + (fi << 4) + (fq << 2);
#pragma unroll
        for (int r = 0; r < 4; r++) {
            const int m = mbase + r;
            const int tok = text[m * NS + sstep];
#pragma unroll
            for (int fj = 0; fj < 2; fj++) {
                const int n = bn + (wc << 5) + (fj << 4) + fr;
                gates[(size_t)m * 2048 + n] =
                    acc[fi][fj][r] + b_ih[n] + b_hh[n] + W_ih_f32[(size_t)n * 608 + 512 + tok];
            }
        }
    }
}

// ---------------------------------------------------------------------------
// Attention (bf16 H_proj/batch_H): e, softmax over t=64, ctx (bf16 out)
// ---------------------------------------------------------------------------
__global__ __launch_bounds__(256) void attn_kernel(
    const unsigned short* __restrict__ H_proj,   // [B*64][512] bf16
    const float* __restrict__ ph,                // [B][512]
    const float* __restrict__ w_score,           // [512]
    const unsigned short* __restrict__ batch_H,  // [B*64][512] bf16
    unsigned short* __restrict__ ctx)            // [B][512] bf16
{
    __shared__ float s_ph[512];
    __shared__ float s_w[512];
    __shared__ float s_e[64];
    __shared__ float s_al[64];
    const int b = blockIdx.x;
    const int tid = threadIdx.x;
    s_ph[tid] = ph[b * 512 + tid];
    s_ph[tid + 256] = ph[b * 512 + 256 + tid];
    s_w[tid] = w_score[tid];
    s_w[tid + 256] = w_score[tid + 256];
    __syncthreads();

    const int w = tid >> 6, lane = tid & 63;
    for (int t = w; t < 64; t += 4) {
        const uint4 hv = *(const uint4*)(H_proj + ((size_t)b * 64 + t) * 512 + lane * 8);
        const int h0 = lane * 8;
        unsigned int ua[4] = {hv.x, hv.y, hv.z, hv.w};
        float acc = 0.f;
#pragma unroll
        for (int j = 0; j < 4; j++) {
            const float e0 = __uint_as_float(ua[j] << 16);
            const float e1 = __uint_as_float(ua[j] & 0xffff0000u);
            acc += tanh_fast(e0 + s_ph[h0 + 2 * j]) * s_w[h0 + 2 * j];
            acc += tanh_fast(e1 + s_ph[h0 + 2 * j + 1]) * s_w[h0 + 2 * j + 1];
        }
#pragma unroll
        for (int off = 32; off; off >>= 1) acc += __shfl_xor(acc, off);
        if (lane == 0) s_e[t] = acc;
    }
    __syncthreads();
    if (tid < 64) {
        float m = -1e30f;
        for (int t = 0; t < 64; ++t) m = fmaxf(m, s_e[t]);
        float sum = 0.f;
        for (int t = 0; t < 64; ++t) sum += __expf(s_e[t] - m);
        s_al[tid] = __expf(s_e[tid] - m) / sum;
    }
    __syncthreads();
    // ctx: 2 packed bf16 cols per thread
    const unsigned int* bH = (const unsigned int*)(batch_H + (size_t)b * 64 * 512);
    float a0 = 0.f, a1 = 0.f;
    for (int t = 0; t < 64; ++t) {
        const unsigned int u = bH[t * 256 + tid];
        const float al = s_al[t];
        a0 = fmaf(al, __uint_as_float(u << 16), a0);
        a1 = fmaf(al, __uint_as_float(u & 0xffff0000u), a1);
    }
    const unsigned int o = ((unsigned int)f2bf(a1) << 16) | (unsigned int)f2bf(a0);
    ((unsigned int*)(ctx + (size_t)b * 512))[tid] = o;
}

// ---------------------------------------------------------------------------
// LSTM pointwise: gates fp32 -> c fp32, h written as bf16 into hs[b][s][:]
// ---------------------------------------------------------------------------
__global__ __launch_bounds__(256) void lstm_pw(
    const float* __restrict__ gates,
    float* __restrict__ c,
    unsigned short* __restrict__ hs,   // [B][NS][512] bf16
    int sstep)
{
    const int idx = blockIdx.x * 256 + threadIdx.x;
    const int b = idx >> 9, hcol = idx & 511;
    const float* g = gates + (size_t)b * 2048;
    const float i_ = sigf(g[hcol]);
    const float f_ = sigf(g[512 + hcol]);
    const float g_ = tanh_fast(g[1024 + hcol]);
    const float o_ = sigf(g[1536 + hcol]);
    const float cn = fmaf(f_, c[idx], i_ * g_);
    c[idx] = cn;
    hs[((size_t)b * NS + sstep) * 512 + hcol] = f2bf(o_ * tanh_fast(cn));
}

// ---------------------------------------------------------------------------
extern "C" void kernel_launch(void* const* d_in, const int* in_sizes, int n_in,
                              void* d_out, int out_size, void* d_ws, size_t ws_size,
                              hipStream_t stream) {
    const float* batch_H = (const float*)d_in[0];   // [512,64,512]
    const int*   text    = (const int*)d_in[1];     // [512,26]
    const float* W_i2h   = (const float*)d_in[2];   // [512,512]
    const float* W_h2h   = (const float*)d_in[3];   // [512,512]
    const float* b_h2h   = (const float*)d_in[4];   // [512]
    const float* w_score = (const float*)d_in[5];   // [1,512]
    const float* W_ih    = (const float*)d_in[6];   // [2048,608]
    const float* b_ih    = (const float*)d_in[7];   // [2048]
    const float* W_hh    = (const float*)d_in[8];   // [2048,512]
    const float* b_hh    = (const float*)d_in[9];   // [2048]
    const float* W_gen   = (const float*)d_in[10];  // [96,512]
    const float* b_gen   = (const float*)d_in[11];  // [96]
    float* out = (float*)d_out;                     // [512,26,96]

    char* wsp = (char*)d_ws;
    auto alloc = [&](size_t bytes) { char* p = wsp; wsp += (bytes + 255) & ~(size_t)255; return p; };
    unsigned short* bH    = (unsigned short*)alloc(32768ull * 512 * 2);
    unsigned short* Hproj = (unsigned short*)alloc(32768ull * 512 * 2);
    unsigned short* hs    = (unsigned short*)alloc(512ull * NS * 512 * 2);
    unsigned short* h0    = (unsigned short*)alloc(512ull * 512 * 2);
    unsigned short* ctx   = (unsigned short*)alloc(512ull * 512 * 2);
    unsigned short* Wi2hb = (unsigned short*)alloc(512ull * 512 * 2);
    unsigned short* Wh2hb = (unsigned short*)alloc(512ull * 512 * 2);
    unsigned short* Wihcb = (unsigned short*)alloc(2048ull * 512 * 2);
    unsigned short* Whhb  = (unsigned short*)alloc(2048ull * 512 * 2);
    unsigned short* Wgenb = (unsigned short*)alloc(96ull * 512 * 2);
    float* ph    = (float*)alloc(512ull * 512 * 4);
    float* gates = (float*)alloc(512ull * 2048 * 4);
    float* cst   = (float*)alloc(512ull * 512 * 4);

    hipMemsetAsync(h0, 0, 512ull * 512 * 2, stream);
    hipMemsetAsync(cst, 0, 512ull * 512 * 4, stream);

    conv_f32_bf16<<<16384, 256, 0, stream>>>(batch_H, bH, 4194304);
    conv_f32_bf16<<<256, 256, 0, stream>>>(W_i2h, Wi2hb, 65536);
    conv_f32_bf16<<<256, 256, 0, stream>>>(W_h2h, Wh2hb, 65536);
    conv_f32_bf16<<<1024, 256, 0, stream>>>(W_hh, Whhb, 262144);
    conv_f32_bf16<<<48, 256, 0, stream>>>(W_gen, Wgenb, 12288);
    conv_wih<<<1024, 256, 0, stream>>>(W_ih, Wihcb);

    // H_proj = batch_H @ W_i2h^T  -> bf16 [32768,512]
    gemm_bf16<0><<<dim3(8, 512), 256, 0, stream>>>(bH, 512, Wi2hb, 512, Hproj, 512, nullptr, 512, 0);

    for (int s = 0; s < NS; ++s) {
        const unsigned short* hprev = s ? hs + (size_t)(s - 1) * 512 : h0;
        const int ldh = s ? NS * 512 : 512;

        // ph = hprev @ W_h2h^T + b_h2h  (f32)
        gemm_bf16<1><<<dim3(8, 8), 256, 0, stream>>>(hprev, ldh, Wh2hb, 512, ph, 512, b_h2h, 512, 0);

        attn_kernel<<<512, 256, 0, stream>>>(Hproj, ph, w_score, bH, ctx);

        gemm_gates_mfma<<<dim3(32, 8), 256, 0, stream>>>(
            ctx, hprev, ldh, Wihcb, Whhb, W_ih, b_ih, b_hh, text, s, gates);

        lstm_pw<<<1024, 256, 0, stream>>>(gates, cst, hs, s);
    }

    // out = hs @ W_gen^T + b_gen  (f32, N=96 masked within 128-wide tiles)
    gemm_bf16<3><<<dim3(2, 208), 256, 0, stream>>>(hs, 512, Wgenb, 512, out, 96, b_gen, 512, 96);
}